// Round 4
// baseline (149.474 us; speedup 1.0000x reference)
//
#include <hip/hip_runtime.h>
#include <hip/hip_bf16.h>

// Chamfer loss, B=8, N=M=8192, D=3, fp32.
// result = (mean_n min_m d2(a_n,b_m) + mean_m min_n d2) / 2
// d2 = a2 + b2 - 2ab; track max_q where q = ab - 0.5*b2, then
// d2_min = max(a2 - 2*max_q, 0).
//
// R4: (a) packed fp32 via v_pk_fma_f32 — b-points stored in LDS as PAIRS
// (xx,yy,zz,-ww as float2) so each pk_fma covers 2 b-points: 3 pk_fma +
// 1 max3 per 2 pairs = 2 insts/pair (was 3.5). (b) pass2+pass3 fused via
// last-block finalize (atomic acc + counter in ws, memset-async to 0).

typedef float v2f __attribute__((ext_vector_type(2)));

#define BATCH   8
#define NPTS    8192
#define BLK     256
#define TOTAL_A (2 * BATCH * NPTS)    // 131072
#define P2_BLOCKS (TOTAL_A / BLK)     // 512

struct alignas(16) BPair { v2f xx, yy, zz, nw; };  // 32 B: 2 b-points

template <int NCH, int GROUPS>
__global__ __launch_bounds__(BLK) void chamfer_pass1_t(
    const float* __restrict__ pred, const float* __restrict__ gt,
    float* __restrict__ partial) {
  constexpr int CH  = NPTS / NCH;          // b-points per chunk
  constexpr int NPAIR = CH / 2;
  constexpr int IL  = GROUPS * 4;          // a-points per thread
  constexpr int PPB = BLK * IL;            // a-points per block
  constexpr int NBv = NPTS / PPB;          // n-tiles

  __shared__ BPair bs[NPAIR];

  const int bid   = blockIdx.x;
  const int chunk = bid & (NCH - 1);
  const int r     = bid / NCH;             // pow2 -> shift
  const int nb    = r & (NBv - 1);
  const int r2    = r / NBv;
  const int batch = r2 & (BATCH - 1);
  const int side  = r2 >> 3;

  const float* A  = (side == 0) ? pred : gt;
  const float* Bp = (side == 0) ? gt : pred;
  const int t = threadIdx.x;

  // stage b-chunk into LDS as pairs: (x0,x1)(y0,y1)(z0,z1)(-w0,-w1),
  // w = 0.5*|b|^2
  const float* bbase = Bp + ((size_t)batch * NPTS + (size_t)chunk * CH) * 3;
  for (int p = t; p < NPAIR; p += BLK) {
    const float* b6 = bbase + (size_t)p * 6;
    float x0 = b6[0], y0 = b6[1], z0 = b6[2];
    float x1 = b6[3], y1 = b6[4], z1 = b6[5];
    BPair bp;
    bp.xx = (v2f){x0, x1};
    bp.yy = (v2f){y0, y1};
    bp.zz = (v2f){z0, z1};
    bp.nw = (v2f){-0.5f * fmaf(x0, x0, fmaf(y0, y0, z0 * z0)),
                  -0.5f * fmaf(x1, x1, fmaf(y1, y1, z1 * z1))};
    bs[p] = bp;
  }
  __syncthreads();

  // load IL a-points per thread: GROUPS groups of 4 consecutive points,
  // each group = 12 consecutive floats = 3 float4 loads (coalesced).
  float ax[IL], ay[IL], az[IL], mq[IL];
  const float* abase = A + ((size_t)batch * NPTS + (size_t)nb * PPB) * 3;
#pragma unroll
  for (int g = 0; g < GROUPS; g++) {
    const int n0 = g * (BLK * 4) + t * 4;
    const float4* a4 = (const float4*)(abase + (size_t)n0 * 3);
    float4 f0 = a4[0], f1 = a4[1], f2 = a4[2];
    ax[g*4+0] = f0.x; ay[g*4+0] = f0.y; az[g*4+0] = f0.z;
    ax[g*4+1] = f0.w; ay[g*4+1] = f1.x; az[g*4+1] = f1.y;
    ax[g*4+2] = f1.z; ay[g*4+2] = f1.w; az[g*4+2] = f2.x;
    ax[g*4+3] = f2.y; ay[g*4+3] = f2.z; az[g*4+3] = f2.w;
#pragma unroll
    for (int k = 0; k < 4; k++) mq[g*4+k] = -1e30f;
  }

  // main loop: per pair = 2 ds_read_b128 + IL*(3 pk_fma + 1 max3)
#pragma unroll 2
  for (int j = 0; j < NPAIR; j++) {
    v2f bx = bs[j].xx, by = bs[j].yy, bz = bs[j].zz, bw = bs[j].nw;
#pragma unroll
    for (int i = 0; i < IL; i++) {
      v2f q = __builtin_elementwise_fma(
                (v2f){ax[i], ax[i]}, bx,
                __builtin_elementwise_fma(
                  (v2f){ay[i], ay[i]}, by,
                  __builtin_elementwise_fma((v2f){az[i], az[i]}, bz, bw)));
      mq[i] = fmaxf(fmaxf(q.x, q.y), mq[i]);   // -> v_max3_f32
    }
  }

  // chunk-major partial: partial[chunk*TOTAL_A + sb*NPTS + n], float4 stores
  const int sb = side * BATCH + batch;
  float* pb = partial + (size_t)chunk * TOTAL_A + (size_t)sb * NPTS + (size_t)nb * PPB;
#pragma unroll
  for (int g = 0; g < GROUPS; g++) {
    const int n0 = g * (BLK * 4) + t * 4;
    float4 v = make_float4(mq[g*4+0], mq[g*4+1], mq[g*4+2], mq[g*4+3]);
    *(float4*)(pb + n0) = v;
  }
}

// Fused combine + global reduce + finalize (last block writes out).
template <int NCH>
__global__ __launch_bounds__(BLK) void chamfer_pass2_t(
    const float* __restrict__ pred, const float* __restrict__ gt,
    const float* __restrict__ partial, float* __restrict__ acc,
    unsigned* __restrict__ counter, float* __restrict__ out) {
  const int gid  = blockIdx.x * BLK + threadIdx.x;   // [0, TOTAL_A)
  const int side = gid >> 16;                        // BATCH*NPTS == 65536
  const int rem  = gid & 65535;                      // batch*NPTS + n

  const float* A = (side == 0) ? pred : gt;
  float x = A[(size_t)rem * 3 + 0];
  float y = A[(size_t)rem * 3 + 1];
  float z = A[(size_t)rem * 3 + 2];
  float a2 = fmaf(x, x, fmaf(y, y, z * z));

  float mq = -1e30f;
#pragma unroll
  for (int c = 0; c < NCH; c++) {
    mq = fmaxf(mq, partial[(size_t)c * TOTAL_A + gid]);   // coalesced
  }
  float d2 = fmaxf(fmaf(-2.0f, mq, a2), 0.0f);

  // block reduction: wave shuffle then LDS across 4 waves
  float v = d2;
  for (int off = 32; off > 0; off >>= 1) v += __shfl_down(v, off);
  __shared__ float wsum[BLK / 64];
  int lane = threadIdx.x & 63, wv = threadIdx.x >> 6;
  if (lane == 0) wsum[wv] = v;
  __syncthreads();
  if (threadIdx.x == 0) {
    float s = wsum[0] + wsum[1] + wsum[2] + wsum[3];
    atomicAdd(acc, s);            // device-scope
    __threadfence();
    unsigned old = atomicAdd(counter, 1u);
    if (old == P2_BLOCKS - 1) {   // last block: all acc adds visible
      __threadfence();
      float total = atomicAdd(acc, 0.0f);   // device-scope read
      out[0] = total * (1.0f / (float)TOTAL_A);  // (s1+s2)/(2*65536)
    }
  }
}

extern "C" void kernel_launch(void* const* d_in, const int* in_sizes, int n_in,
                              void* d_out, int out_size, void* d_ws, size_t ws_size,
                              hipStream_t stream) {
  const float* pred = (const float*)d_in[0];
  const float* gt   = (const float*)d_in[1];
  float* out = (float*)d_out;
  float* partial = (float*)d_ws;

  const size_t need32 = (size_t)TOTAL_A * 32 * sizeof(float) + 4096;  // ~16.8 MB

  if (ws_size >= need32) {
    constexpr int NCH = 32, GROUPS = 4;            // IL=16, NB=2
    float* acc = partial + (size_t)TOTAL_A * NCH;
    unsigned* counter = (unsigned*)(acc + 1);
    hipMemsetAsync(acc, 0, 2 * sizeof(float), stream);   // acc=0, counter=0
    const int p1_blocks = 2 * BATCH * (NPTS / (BLK * GROUPS * 4)) * NCH;  // 1024
    chamfer_pass1_t<NCH, GROUPS><<<p1_blocks, BLK, 0, stream>>>(pred, gt, partial);
    chamfer_pass2_t<NCH><<<P2_BLOCKS, BLK, 0, stream>>>(pred, gt, partial, acc, counter, out);
  } else {
    constexpr int NCH = 16, GROUPS = 2;            // IL=8, NB=4 (8.4 MB scratch)
    float* acc = partial + (size_t)TOTAL_A * NCH;
    unsigned* counter = (unsigned*)(acc + 1);
    hipMemsetAsync(acc, 0, 2 * sizeof(float), stream);
    const int p1_blocks = 2 * BATCH * (NPTS / (BLK * GROUPS * 4)) * NCH;  // 1024
    chamfer_pass1_t<NCH, GROUPS><<<p1_blocks, BLK, 0, stream>>>(pred, gt, partial);
    chamfer_pass2_t<NCH><<<P2_BLOCKS, BLK, 0, stream>>>(pred, gt, partial, acc, counter, out);
  }
}

// Round 5
// 146.048 us; speedup vs baseline: 1.0235x; 1.0235x over previous
//
#include <hip/hip_runtime.h>
#include <hip/hip_bf16.h>

// Chamfer loss, B=8, N=M=8192, D=3, fp32.
// result = (mean_n min_m d2(a_n,b_m) + mean_m min_n d2) / 2
// d2 = a2 + b2 - 2ab; track max_q where q = ab - 0.5*b2, then
// d2_min = max(a2 - 2*max_q, 0).
//
// R5: (a) packed fp32 retry with the R4 failure fixed: A-points are pair-
// packed ONCE at load time (v2f ax2/ay2/az2), b-broadcast dups hoisted per
// j-pair (8 movs / 64 pk-insts); LDS b-layout stays float4 (R3's conflict-
// free form). 2.25 insts/pair vs R3's 3.5. Worst-case scalarization == R3.
// (b) waves split the block's m-range 4-way, combine maxes through LDS ->
// global partial shrinks 16.8 MB -> 4.2 MB (NCH=8). (c) pass2+finalize
// fused via last-block atomic (validated in R4).

typedef float v2f __attribute__((ext_vector_type(2)));

#define BATCH   8
#define NPTS    8192
#define BLK     256
#define TOTAL_A (2 * BATCH * NPTS)    // 131072
#define NCH     8                     // m-chunks across blocks
#define CH      (NPTS / NCH)          // 1024 b-points per block
#define CHW     (CH / 4)              // 256 b-points per wave
#define PPB     1024                  // a-points per block (shared by all waves)
#define NB      (NPTS / PPB)          // 8
#define GRID1   (2 * BATCH * NB * NCH)  // 1024
#define P2_BLOCKS (TOTAL_A / BLK)     // 512

__global__ __launch_bounds__(BLK, 4) void chamfer_pass1(
    const float* __restrict__ pred, const float* __restrict__ gt,
    float* __restrict__ partial) {
  __shared__ float4 bs[CH];          // 16 KB: (x, y, z, -0.5|b|^2)
  __shared__ float  red[4 * PPB];    // 16 KB: per-wave maxes

  const int bid   = blockIdx.x;
  const int chunk = bid & (NCH - 1);
  const int r     = bid >> 3;
  const int nb    = r & (NB - 1);
  const int r2    = r >> 3;
  const int batch = r2 & (BATCH - 1);
  const int side  = r2 >> 3;

  const float* A  = (side == 0) ? pred : gt;
  const float* Bp = (side == 0) ? gt : pred;
  const int t = threadIdx.x;
  const int l = t & 63;
  const int w = t >> 6;

  // stage b-chunk: thread t stages points 4t..4t+3 (3 coalesced float4 reads)
  {
    const float* bbase = Bp + ((size_t)batch * NPTS + (size_t)chunk * CH) * 3;
    const float4* b4 = (const float4*)bbase + t * 3;
    float4 f0 = b4[0], f1 = b4[1], f2 = b4[2];
    bs[t*4+0] = make_float4(f0.x, f0.y, f0.z,
                            -0.5f * fmaf(f0.x, f0.x, fmaf(f0.y, f0.y, f0.z * f0.z)));
    bs[t*4+1] = make_float4(f0.w, f1.x, f1.y,
                            -0.5f * fmaf(f0.w, f0.w, fmaf(f1.x, f1.x, f1.y * f1.y)));
    bs[t*4+2] = make_float4(f1.z, f1.w, f2.x,
                            -0.5f * fmaf(f1.z, f1.z, fmaf(f1.w, f1.w, f2.x * f2.x)));
    bs[t*4+3] = make_float4(f2.y, f2.z, f2.w,
                            -0.5f * fmaf(f2.y, f2.y, fmaf(f2.z, f2.z, f2.w * f2.w)));
  }

  // load 16 a-points as 8 packed pairs (same points for every wave; L1-hot).
  // pair p = g*2+k holds points n_local = g*256 + l*4 + 2k + {0,1}
  v2f ax2[8], ay2[8], az2[8];
  float mq[16];
  const float* abase = A + ((size_t)batch * NPTS + (size_t)nb * PPB) * 3;
#pragma unroll
  for (int g = 0; g < 4; g++) {
    const float4* a4 = (const float4*)(abase + (size_t)(g * 256 + l * 4) * 3);
    float4 f0 = a4[0], f1 = a4[1], f2 = a4[2];
    ax2[g*2+0] = (v2f){f0.x, f0.w}; ay2[g*2+0] = (v2f){f0.y, f1.x}; az2[g*2+0] = (v2f){f0.z, f1.y};
    ax2[g*2+1] = (v2f){f1.z, f2.y}; ay2[g*2+1] = (v2f){f1.w, f2.z}; az2[g*2+1] = (v2f){f2.x, f2.w};
#pragma unroll
    for (int k = 0; k < 4; k++) mq[g*4+k] = -1e30f;
  }
  __syncthreads();

  // main loop: wave w covers b-points [w*CHW, (w+1)*CHW)
  const float4* bw = bs + w * CHW;
  for (int j = 0; j < CHW; j += 2) {
    float4 b0 = bw[j], b1 = bw[j + 1];
    v2f b0x = (v2f){b0.x, b0.x}, b0y = (v2f){b0.y, b0.y};
    v2f b0z = (v2f){b0.z, b0.z}, b0w = (v2f){b0.w, b0.w};
    v2f b1x = (v2f){b1.x, b1.x}, b1y = (v2f){b1.y, b1.y};
    v2f b1z = (v2f){b1.z, b1.z}, b1w = (v2f){b1.w, b1.w};
#pragma unroll
    for (int p = 0; p < 8; p++) {
      v2f q0 = __builtin_elementwise_fma(ax2[p], b0x,
               __builtin_elementwise_fma(ay2[p], b0y,
               __builtin_elementwise_fma(az2[p], b0z, b0w)));
      v2f q1 = __builtin_elementwise_fma(ax2[p], b1x,
               __builtin_elementwise_fma(ay2[p], b1y,
               __builtin_elementwise_fma(az2[p], b1z, b1w)));
      mq[2*p]   = fmaxf(fmaxf(q0.x, q1.x), mq[2*p]);     // v_max3_f32
      mq[2*p+1] = fmaxf(fmaxf(q0.y, q1.y), mq[2*p+1]);
    }
  }

  // cross-wave max-combine through LDS
#pragma unroll
  for (int g = 0; g < 4; g++) {
    *(float4*)(red + w * PPB + g * 256 + l * 4) =
        make_float4(mq[g*4+0], mq[g*4+1], mq[g*4+2], mq[g*4+3]);
  }
  __syncthreads();
  // thread t finalizes a-points n_local = 4t..4t+3
  float4 m0 = *(const float4*)(red + 0 * PPB + t * 4);
  float4 m1 = *(const float4*)(red + 1 * PPB + t * 4);
  float4 m2 = *(const float4*)(red + 2 * PPB + t * 4);
  float4 m3 = *(const float4*)(red + 3 * PPB + t * 4);
  float4 mm;
  mm.x = fmaxf(fmaxf(m0.x, m1.x), fmaxf(m2.x, m3.x));
  mm.y = fmaxf(fmaxf(m0.y, m1.y), fmaxf(m2.y, m3.y));
  mm.z = fmaxf(fmaxf(m0.z, m1.z), fmaxf(m2.z, m3.z));
  mm.w = fmaxf(fmaxf(m0.w, m1.w), fmaxf(m2.w, m3.w));

  // chunk-major partial: partial[chunk*TOTAL_A + sb*NPTS + nb*PPB + n_local]
  const int sb = side * BATCH + batch;
  float* pb = partial + (size_t)chunk * TOTAL_A + (size_t)sb * NPTS + (size_t)nb * PPB;
  *(float4*)(pb + t * 4) = mm;
}

// Fused combine + global reduce + finalize (last block writes out).
__global__ __launch_bounds__(BLK) void chamfer_pass2(
    const float* __restrict__ pred, const float* __restrict__ gt,
    const float* __restrict__ partial, float* __restrict__ acc,
    unsigned* __restrict__ counter, float* __restrict__ out) {
  const int gid  = blockIdx.x * BLK + threadIdx.x;   // [0, TOTAL_A)
  const int side = gid >> 16;                        // BATCH*NPTS == 65536
  const int rem  = gid & 65535;

  const float* A = (side == 0) ? pred : gt;
  float x = A[(size_t)rem * 3 + 0];
  float y = A[(size_t)rem * 3 + 1];
  float z = A[(size_t)rem * 3 + 2];
  float a2 = fmaf(x, x, fmaf(y, y, z * z));

  float mq = -1e30f;
#pragma unroll
  for (int c = 0; c < NCH; c++) {
    mq = fmaxf(mq, partial[(size_t)c * TOTAL_A + gid]);   // coalesced
  }
  float d2 = fmaxf(fmaf(-2.0f, mq, a2), 0.0f);

  float v = d2;
  for (int off = 32; off > 0; off >>= 1) v += __shfl_down(v, off);
  __shared__ float wsum[BLK / 64];
  int lane = threadIdx.x & 63, wv = threadIdx.x >> 6;
  if (lane == 0) wsum[wv] = v;
  __syncthreads();
  if (threadIdx.x == 0) {
    float s = wsum[0] + wsum[1] + wsum[2] + wsum[3];
    atomicAdd(acc, s);            // device-scope
    __threadfence();
    unsigned old = atomicAdd(counter, 1u);
    if (old == P2_BLOCKS - 1) {   // last block: all acc adds visible
      __threadfence();
      float total = atomicAdd(acc, 0.0f);
      out[0] = total * (1.0f / (float)TOTAL_A);  // (s1+s2)/(2*65536)
    }
  }
}

extern "C" void kernel_launch(void* const* d_in, const int* in_sizes, int n_in,
                              void* d_out, int out_size, void* d_ws, size_t ws_size,
                              hipStream_t stream) {
  const float* pred = (const float*)d_in[0];
  const float* gt   = (const float*)d_in[1];
  float* out = (float*)d_out;

  float* partial = (float*)d_ws;                       // 4.2 MB
  float* acc = partial + (size_t)TOTAL_A * NCH;
  unsigned* counter = (unsigned*)(acc + 1);
  hipMemsetAsync(acc, 0, 2 * sizeof(float), stream);   // acc=0, counter=0

  chamfer_pass1<<<GRID1, BLK, 0, stream>>>(pred, gt, partial);
  chamfer_pass2<<<P2_BLOCKS, BLK, 0, stream>>>(pred, gt, partial, acc, counter, out);
}